// Round 19
// baseline (185.184 us; speedup 1.0000x reference)
//
#include <hip/hip_runtime.h>
#include <math.h>

#define SEQ 2048
#define EMB 1024
#define NH 16
#define HD 64
#define BH 64          // B*H = 4*16
#define L2E 1.44269504088896340736f

typedef __attribute__((ext_vector_type(8))) short bf16x8;
typedef __attribute__((ext_vector_type(4))) float f32x4;
typedef __attribute__((ext_vector_type(16))) float f32x16;
typedef __attribute__((ext_vector_type(4))) unsigned short u16x4;

__device__ __forceinline__ unsigned short f2bf(float f) {
  union { float fv; unsigned u; } v; v.fv = f;
  return (unsigned short)((v.u + 0x7FFFu + ((v.u >> 16) & 1u)) >> 16);
}

__device__ __forceinline__ unsigned cvt_pk_bf16(float lo, float hi) {
  unsigned r;
  asm("v_cvt_pk_bf16_f32 %0, %1, %2" : "=v"(r) : "v"(lo), "v"(hi));
  return r;
}

__device__ __forceinline__ void gl_lds16(const void* g, void* l) {
  __builtin_amdgcn_global_load_lds(
      (const __attribute__((address_space(1))) unsigned*)g,
      (__attribute__((address_space(3))) unsigned*)l, 16, 0, 0);
}

// ---------- weight transpose+convert+scale, all 3 weights in one launch ----------
__global__ __launch_bounds__(256) void k_wt3(const float* __restrict__ Wq,
                                             const float* __restrict__ Wk,
                                             const float* __restrict__ Wv,
                                             unsigned short* __restrict__ tq,
                                             unsigned short* __restrict__ tk,
                                             unsigned short* __restrict__ tv) {
  int z = blockIdx.z;
  const float* W = (z == 0) ? Wq : (z == 1) ? Wk : Wv;
  unsigned short* Wt = (z == 0) ? tq : (z == 1) ? tk : tv;
  const float scale = (z == 0) ? 0.125f * L2E : 1.0f;  // fold score scale into Wq

  __shared__ float tile[32][33];
  int j0 = blockIdx.x * 32, i0 = blockIdx.y * 32;
  int tx = threadIdx.x & 31, ty = threadIdx.x >> 5;
#pragma unroll
  for (int r = 0; r < 32; r += 8)
    tile[ty + r][tx] = W[(i0 + ty + r) * EMB + j0 + tx];
  __syncthreads();
#pragma unroll
  for (int r = 0; r < 32; r += 8)
    Wt[(j0 + ty + r) * EMB + i0 + tx] = f2bf(tile[tx][ty + r] * scale);
}

// ---------- projection GEMM: A = fp32 reg-staged 2-deep; B = gl_lds 3-slot ring ----------
// (round-16 proven config, verbatim)
__global__ __launch_bounds__(256) void k_proj(
    const float* __restrict__ xq, const float* __restrict__ xk,
    const float* __restrict__ xv,
    const unsigned short* __restrict__ w0, const unsigned short* __restrict__ w1,
    const unsigned short* __restrict__ w2,
    unsigned short* __restrict__ o0, unsigned short* __restrict__ o1,
    unsigned short* __restrict__ o2) {
  int z = blockIdx.z;
  const float* X = (z == 0) ? xq : (z == 1) ? xk : xv;
  const unsigned short* Wt = (z == 0) ? w0 : (z == 1) ? w1 : w2;
  unsigned short* O = (z == 0) ? o0 : (z == 1) ? o1 : o2;

  __shared__ __align__(16) unsigned short As[2][128 * 64];  // 32KB, swizzled
  __shared__ __align__(16) unsigned short Bs[3 * 128 * 64]; // 48KB, 3-slot ring, swizzled

  int tid = threadIdx.x;
  int lane = tid & 63, w = tid >> 6;
  int ln15 = lane & 15, lg = lane >> 4;
  int wr = w >> 1, wc = w & 1;
  int row0 = blockIdx.x * 128, col0 = blockIdx.y * 128;

  const char* Xb = (const char*)X;
  const char* Wb = (const char*)Wt;

  f32x4 acc[4][4];
#pragma unroll
  for (int i = 0; i < 4; ++i)
#pragma unroll
    for (int j = 0; j < 4; ++j) acc[i][j] = (f32x4){0.f, 0.f, 0.f, 0.f};

  int oc[4], dswz[4];
  size_t srcA[4];
#pragma unroll
  for (int c = 0; c < 4; ++c) {
    oc[c] = w * 4096 + c * 1024 + lane * 16;
    dswz[c] = oc[c] ^ (((oc[c] >> 7) & 7) << 4);
    srcA[c] = (size_t)(row0 + (oc[c] >> 7)) * (EMB * 4) + (size_t)(oc[c] & 127) * 2;
  }
  int soB[4];
#pragma unroll
  for (int c = 0; c < 4; ++c) soB[c] = oc[c] ^ (((oc[c] >> 7) & 7) << 4);

  f32x4 arA[4][2], arB[4][2];
  auto ldA_A = [&](int kt) {
#pragma unroll
    for (int c = 0; c < 4; ++c) {
      const char* p = Xb + srcA[c] + kt * 256;
      arA[c][0] = *(const f32x4*)p;
      arA[c][1] = *(const f32x4*)(p + 16);
    }
  };
  auto ldA_B = [&](int kt) {
#pragma unroll
    for (int c = 0; c < 4; ++c) {
      const char* p = Xb + srcA[c] + kt * 256;
      arB[c][0] = *(const f32x4*)p;
      arB[c][1] = *(const f32x4*)(p + 16);
    }
  };
  auto wrA_A = [&](int buf) {
#pragma unroll
    for (int c = 0; c < 4; ++c) {
      union { unsigned u[4]; bf16x8 v; } pk;
      pk.u[0] = cvt_pk_bf16(arA[c][0][0], arA[c][0][1]);
      pk.u[1] = cvt_pk_bf16(arA[c][0][2], arA[c][0][3]);
      pk.u[2] = cvt_pk_bf16(arA[c][1][0], arA[c][1][1]);
      pk.u[3] = cvt_pk_bf16(arA[c][1][2], arA[c][1][3]);
      *(bf16x8*)((char*)As[buf] + dswz[c]) = pk.v;
    }
  };
  auto wrA_B = [&](int buf) {
#pragma unroll
    for (int c = 0; c < 4; ++c) {
      union { unsigned u[4]; bf16x8 v; } pk;
      pk.u[0] = cvt_pk_bf16(arB[c][0][0], arB[c][0][1]);
      pk.u[1] = cvt_pk_bf16(arB[c][0][2], arB[c][0][3]);
      pk.u[2] = cvt_pk_bf16(arB[c][1][0], arB[c][1][1]);
      pk.u[3] = cvt_pk_bf16(arB[c][1][2], arB[c][1][3]);
      *(bf16x8*)((char*)As[buf] + dswz[c]) = pk.v;
    }
  };
  auto stageB = [&](int slot, int kt) {
#pragma unroll
    for (int c = 0; c < 4; ++c)
      gl_lds16(Wb + (size_t)(col0 + (soB[c] >> 7)) * (EMB * 2) + kt * 128 + (soB[c] & 127),
               (char*)Bs + slot * 16384 + w * 4096 + c * 1024);
  };

  auto mfmaStep = [&](int cur, int bslot) {
    const char* bbase = (const char*)Bs + bslot * 16384;
#pragma unroll
    for (int ks = 0; ks < 2; ++ks) {
      bf16x8 a[4], bb[4];
#pragma unroll
      for (int i = 0; i < 4; ++i) {
        int row = wr * 64 + i * 16 + ln15;
        int ba = (row * 128 + ks * 64 + lg * 16) ^ ((row & 7) << 4);
        a[i] = *(const bf16x8*)((const char*)As[cur] + ba);
      }
#pragma unroll
      for (int j = 0; j < 4; ++j) {
        int row = wc * 64 + j * 16 + ln15;
        int ba = (row * 128 + ks * 64 + lg * 16) ^ ((row & 7) << 4);
        bb[j] = *(const bf16x8*)(bbase + ba);
      }
      __builtin_amdgcn_s_setprio(1);
#pragma unroll
      for (int i = 0; i < 4; ++i)
#pragma unroll
        for (int j = 0; j < 4; ++j)
          acc[i][j] = __builtin_amdgcn_mfma_f32_16x16x32_bf16(a[i], bb[j], acc[i][j], 0, 0, 0);
      __builtin_amdgcn_s_setprio(0);
    }
  };

  auto vbar = [&]() {
    asm volatile("s_waitcnt vmcnt(12) lgkmcnt(0)" ::: "memory");
    __builtin_amdgcn_s_barrier();
    __builtin_amdgcn_sched_barrier(0);
  };

  // prologue
  ldA_A(0);
  stageB(0, 0);
  stageB(1, 1);
  wrA_A(0);
  ldA_B(1);
  vbar();

#pragma unroll
  for (int kp = 0; kp < 8; ++kp) {
    const int kte = 2 * kp;
    if (kte + 2 <= 15) stageB((kte + 2) % 3, kte + 2);
    if (kte < 14) ldA_A(kte + 2);
    mfmaStep(0, kte % 3);
    wrA_B(1);
    vbar();

    const int kto = 2 * kp + 1;
    if (kto + 2 <= 15) stageB((kto + 2) % 3, kto + 2);
    if (kto < 14) ldA_B(kto + 2);
    mfmaStep(1, kto % 3);
    if (kto < 15) wrA_A(0);
    vbar();
  }

  if (z == 2) {
#pragma unroll
    for (int i = 0; i < 4; ++i) {
#pragma unroll
      for (int j = 0; j < 4; ++j) {
        int col = col0 + wc * 64 + j * 16 + ln15;
        int h = col >> 6, d = col & 63;
        int rowb = row0 + wr * 64 + i * 16 + lg * 4;
        int b = rowb >> 11, s = rowb & (SEQ - 1);
        u16x4 hv;
#pragma unroll
        for (int r = 0; r < 4; ++r) hv[r] = f2bf(acc[i][j][r]);
        *(u16x4*)&O[(((size_t)(b * NH + h) * HD) + d) * SEQ + s] = hv;
      }
    }
  } else {
#pragma unroll
    for (int i = 0; i < 4; ++i) {
#pragma unroll
      for (int j = 0; j < 4; ++j) {
#pragma unroll
        for (int r = 0; r < 4; ++r) {
          int row = row0 + wr * 64 + i * 16 + lg * 4 + r;
          int col = col0 + wc * 64 + j * 16 + ln15;
          int b = row >> 11, s = row & (SEQ - 1);
          int h = col >> 6, d = col & 63;
          O[(((size_t)(b * NH + h) * SEQ) + s) * HD + d] = f2bf(acc[i][j][r]);
        }
      }
    }
  }
}

// ---------- flash attention, KV-split-2: each block does 1024 keys; exact partials ----------
// grid = 1024 (4 blocks/CU = 8 waves/SIMD); loop structure identical to the proven
// round-12 form, offsets by half*1024 keys; writes unnormalized ctx + lsum partials.
__global__ __launch_bounds__(512) void k_attn(const unsigned short* __restrict__ Q,
                                              const unsigned short* __restrict__ K,
                                              const unsigned short* __restrict__ Vt,
                                              float* __restrict__ pctx,
                                              float* __restrict__ pl) {
  __shared__ __align__(16) unsigned short Klds[2 * 32 * 64];  // 2 slots x 4KB, [key][d] swz
  __shared__ __align__(16) unsigned short Vlds[2 * 64 * 64];  // 2 slots x 8KB, [d][64key] swz

  const int id = blockIdx.x;
  const int swz = (id & 7) * 128 + (id >> 3);   // 8 consecutive bh per XCD
  const int bh = swz >> 4;
  const int qb = (swz >> 1) & 7;
  const int half = swz & 1;
  const int kt0 = half * 32;                    // K tile base (32-key units)
  const int vt0 = half * 16;                    // V tile base (64-key units)

  const int tid = threadIdx.x;
  const int w = tid >> 6, lane = tid & 63;
  const int q31 = lane & 31;
  const int hi = lane >> 5;
  const int q0 = qb * 256 + w * 32;

  const unsigned short* Qb = Q + (size_t)bh * SEQ * HD;
  const char* Kb = (const char*)(K + (size_t)bh * SEQ * HD);
  const char* Vb = (const char*)(Vt + (size_t)bh * HD * SEQ);

  bf16x8 qf[4];
#pragma unroll
  for (int kk = 0; kk < 4; ++kk)
    qf[kk] = *(const bf16x8*)&Qb[(q0 + q31) * HD + kk * 16 + hi * 8];

  f32x16 ctx[2];
#pragma unroll
  for (int db = 0; db < 2; ++db)
#pragma unroll
    for (int r = 0; r < 16; ++r) ctx[db][r] = 0.f;

  f32x16 zero16;
#pragma unroll
  for (int r = 0; r < 16; ++r) zero16[r] = 0.f;
  union { unsigned u[4]; bf16x8 v; } onesf;
#pragma unroll
  for (int r = 0; r < 4; ++r) onesf.u[r] = 0x3F803F80u;
  f32x16 lsum = zero16;  // row-sums of P, C-layout rows == ctx rows

  const int sw = (q31 & 7) << 4;
  int kaddr[4];
#pragma unroll
  for (int kk = 0; kk < 4; ++kk)
    kaddr[kk] = q31 * 128 + (((kk * 32) | (hi * 16)) ^ sw);
  int vaddr[2][2];
#pragma unroll
  for (int pi = 0; pi < 2; ++pi)
#pragma unroll
    for (int j = 0; j < 2; ++j)
      vaddr[pi][j] = q31 * 128 + (((pi * 64) | (j * 32) | (hi * 16)) ^ sw);

  const int o0 = w * 1024 + lane * 16;
  const int os0 = o0 ^ (((o0 >> 7) & 7) << 4);

  auto stageK = [&](int slot, int kt) {
    if (w < 4)
      gl_lds16(Kb + (size_t)kt * 4096 + os0, (char*)Klds + slot * 4096 + w * 1024);
  };
  auto stageV = [&](int slot, int vt) {
    gl_lds16(Vb + (size_t)(os0 >> 7) * (SEQ * 2) + vt * 128 + (os0 & 127),
             (char*)Vlds + slot * 8192 + w * 1024);
  };

  auto barrierC = [&]() {
    if (w < 4) asm volatile("s_waitcnt vmcnt(1)" ::: "memory");
    __builtin_amdgcn_s_barrier();
    __builtin_amdgcn_sched_barrier(0);
  };

  auto qk = [&](f32x16& sx, const char* kbase) {
    __builtin_amdgcn_s_setprio(1);
    bf16x8 kf0 = *(const bf16x8*)(kbase + kaddr[0]);
    sx = __builtin_amdgcn_mfma_f32_32x32x16_bf16(kf0, qf[0], zero16, 0, 0, 0);
#pragma unroll
    for (int kk = 1; kk < 4; ++kk) {
      bf16x8 kf = *(const bf16x8*)(kbase + kaddr[kk]);
      sx = __builtin_amdgcn_mfma_f32_32x32x16_bf16(kf, qf[kk], sx, 0, 0, 0);
    }
    __builtin_amdgcn_s_setprio(0);
  };

  auto smpv = [&](f32x16& sx, int pinIdx, int vb) {
#pragma unroll
    for (int r = 0; r < 16; ++r) sx[r] = __builtin_amdgcn_exp2f(sx[r]);

    unsigned a0 = cvt_pk_bf16(sx[0], sx[1]);
    unsigned a1 = cvt_pk_bf16(sx[2], sx[3]);
    unsigned a2 = cvt_pk_bf16(sx[4], sx[5]);
    unsigned a3 = cvt_pk_bf16(sx[6], sx[7]);
    unsigned a4 = cvt_pk_bf16(sx[8], sx[9]);
    unsigned a5 = cvt_pk_bf16(sx[10], sx[11]);
    unsigned a6 = cvt_pk_bf16(sx[12], sx[13]);
    unsigned a7 = cvt_pk_bf16(sx[14], sx[15]);
    asm volatile("v_permlane32_swap_b32 %0, %1" : "+v"(a0), "+v"(a2));
    asm volatile("v_permlane32_swap_b32 %0, %1" : "+v"(a1), "+v"(a3));
    asm volatile("v_permlane32_swap_b32 %0, %1" : "+v"(a4), "+v"(a6));
    asm volatile("v_permlane32_swap_b32 %0, %1" : "+v"(a5), "+v"(a7));
    union { unsigned u[4]; bf16x8 v; } pa_lo, pa_hi;
    pa_lo.u[0] = a0; pa_lo.u[1] = a1; pa_lo.u[2] = a2; pa_lo.u[3] = a3;
    pa_hi.u[0] = a4; pa_hi.u[1] = a5; pa_hi.u[2] = a6; pa_hi.u[3] = a7;

    const char* vbp = (const char*)Vlds + vb;
    __builtin_amdgcn_s_setprio(1);
    lsum = __builtin_amdgcn_mfma_f32_32x32x16_bf16(pa_lo.v, onesf.v, lsum, 0, 0, 0);
    lsum = __builtin_amdgcn_mfma_f32_32x32x16_bf16(pa_hi.v, onesf.v, lsum, 0, 0, 0);
#pragma unroll
    for (int db = 0; db < 2; ++db) {
      bf16x8 v0 = *(const bf16x8*)(vbp + db * 4096 + vaddr[pinIdx][0]);
      bf16x8 v1 = *(const bf16x8*)(vbp + db * 4096 + vaddr[pinIdx][1]);
      ctx[db] = __builtin_amdgcn_mfma_f32_32x32x16_bf16(pa_lo.v, v0, ctx[db], 0, 0, 0);
      ctx[db] = __builtin_amdgcn_mfma_f32_32x32x16_bf16(pa_hi.v, v1, ctx[db], 0, 0, 0);
    }
    __builtin_amdgcn_s_setprio(0);
  };

  const char* K0 = (const char*)Klds;
  const char* K1 = (const char*)Klds + 4096;
  f32x16 sA, sB;

  stageK(0, kt0);
  stageV(0, vt0);
  barrierC();
  qk(sA, K0);          // local t=0
  stageK(1, kt0 + 1);
  __syncthreads();     // drains V + K(1)

  for (int tp = 0; tp < 15; ++tp) {
    const int vb = (tp & 1) << 13;
    qk(sB, K1);
    stageK(0, kt0 + 2 * tp + 2);
    stageV((tp + 1) & 1, vt0 + tp + 1);
    smpv(sA, 0, vb);
    barrierC();          // K(2tp+2) ready; V(tp+1) allowed in flight
    qk(sA, K0);
    stageK(1, kt0 + 2 * tp + 3);
    smpv(sB, 1, vb);
    __syncthreads();     // drains V(tp+1) + K(2tp+3)
  }
  qk(sB, K1);
  smpv(sA, 0, 8192);     // V tile 15 staged at slot 1
  smpv(sB, 1, 8192);

  // ---- partial epilogue: pctx[half][bh][q][d] = ctx (unnormalized); pl[half][bh][q] = lsum
  float* pc = pctx + ((size_t)(half * BH + bh) * SEQ) * HD;
#pragma unroll
  for (int db = 0; db < 2; ++db) {
#pragma unroll
    for (int r = 0; r < 16; ++r) {
      int q = q0 + (r & 3) + 8 * (r >> 2) + 4 * hi;
      pc[(size_t)q * HD + db * 32 + q31] = ctx[db][r];
    }
  }
  if (q31 == 0) {
    float* plb = pl + (size_t)(half * BH + bh) * SEQ;
#pragma unroll
    for (int r = 0; r < 16; ++r) {
      int q = q0 + (r & 3) + 8 * (r >> 2) + 4 * hi;
      plb[q] = lsum[r];
    }
  }
}

// ---------- exact combine: out = (ctx0 + ctx1) / (l0 + l1) ----------
__global__ __launch_bounds__(256) void k_comb(const float* __restrict__ pctx,
                                              const float* __restrict__ pl,
                                              float* __restrict__ out) {
  const size_t HALF = (size_t)BH * SEQ * HD;   // 8M floats
  int idx = blockIdx.x * 256 + threadIdx.x;    // 0 .. 64*2048*16-1 (f32x4 chunks)
  int bh = idx >> 15;                          // 2048 * 16
  int q = (idx >> 4) & (SEQ - 1);
  int dc = idx & 15;
  size_t o = ((size_t)bh * SEQ + q) * HD + dc * 4;
  f32x4 c0 = *(const f32x4*)(pctx + o);
  f32x4 c1 = *(const f32x4*)(pctx + HALF + o);
  float li = 1.0f / (pl[(size_t)bh * SEQ + q] + pl[(size_t)(BH + bh) * SEQ + q]);
  int b = bh >> 4, h = bh & 15;
  f32x4 rv;
#pragma unroll
  for (int j = 0; j < 4; ++j) rv[j] = (c0[j] + c1[j]) * li;
  *(f32x4*)(out + ((size_t)(b * SEQ + q)) * (NH * HD) + h * HD + dc * 4) = rv;
}

extern "C" void kernel_launch(void* const* d_in, const int* in_sizes, int n_in,
                              void* d_out, int out_size, void* d_ws, size_t ws_size,
                              hipStream_t stream) {
  (void)in_sizes; (void)n_in; (void)out_size; (void)ws_size;
  const float* queries = (const float*)d_in[0];
  const float* keys    = (const float*)d_in[1];
  const float* values  = (const float*)d_in[2];
  const float* Wq = (const float*)d_in[3];
  const float* Wk = (const float*)d_in[4];
  const float* Wv = (const float*)d_in[5];
  float* out = (float*)d_out;

  char* ws = (char*)d_ws;
  const size_t MB = 1024 * 1024;
  unsigned short* q_ws = (unsigned short*)(ws);             // [bh][s][d] bf16 (16MB)
  unsigned short* k_ws = (unsigned short*)(ws + 16 * MB);   // [bh][s][d] bf16
  unsigned short* v_ws = (unsigned short*)(ws + 32 * MB);   // [bh][d][s] bf16 (transposed)
  unsigned short* wtq  = (unsigned short*)(ws + 48 * MB);   // Wt[n][k] bf16 (2MB each)
  unsigned short* wtk  = (unsigned short*)(ws + 50 * MB);
  unsigned short* wtv  = (unsigned short*)(ws + 52 * MB);
  float* pctx = (float*)(ws + 56 * MB);                     // 2 x 32MB partial ctx
  float* pl   = (float*)(ws + 120 * MB);                    // 2 x 512KB partial l

  k_wt3<<<dim3(32, 32, 3), 256, 0, stream>>>(Wq, Wk, Wv, wtq, wtk, wtv);
  k_proj<<<dim3(64, 8, 3), 256, 0, stream>>>(queries, keys, values,
                                             wtq, wtk, wtv, q_ws, k_ws, v_ws);
  k_attn<<<dim3(1024), 512, 0, stream>>>(q_ws, k_ws, v_ws, pctx, pl);
  k_comb<<<dim3(8192), 256, 0, stream>>>(pctx, pl, out);
}

// Round 20
// 161.066 us; speedup vs baseline: 1.1497x; 1.1497x over previous
//
#include <hip/hip_runtime.h>
#include <math.h>

#define SEQ 2048
#define EMB 1024
#define NH 16
#define HD 64
#define BH 64          // B*H = 4*16
#define L2E 1.44269504088896340736f

typedef __attribute__((ext_vector_type(8))) short bf16x8;
typedef __attribute__((ext_vector_type(4))) float f32x4;
typedef __attribute__((ext_vector_type(16))) float f32x16;
typedef __attribute__((ext_vector_type(4))) unsigned short u16x4;

__device__ __forceinline__ unsigned short f2bf(float f) {
  union { float fv; unsigned u; } v; v.fv = f;
  return (unsigned short)((v.u + 0x7FFFu + ((v.u >> 16) & 1u)) >> 16);
}

__device__ __forceinline__ unsigned cvt_pk_bf16(float lo, float hi) {
  unsigned r;
  asm("v_cvt_pk_bf16_f32 %0, %1, %2" : "=v"(r) : "v"(lo), "v"(hi));
  return r;
}

__device__ __forceinline__ void gl_lds16(const void* g, void* l) {
  __builtin_amdgcn_global_load_lds(
      (const __attribute__((address_space(1))) unsigned*)g,
      (__attribute__((address_space(3))) unsigned*)l, 16, 0, 0);
}

// ---------- weight transpose+convert+scale, all 3 weights in one launch ----------
__global__ __launch_bounds__(256) void k_wt3(const float* __restrict__ Wq,
                                             const float* __restrict__ Wk,
                                             const float* __restrict__ Wv,
                                             unsigned short* __restrict__ tq,
                                             unsigned short* __restrict__ tk,
                                             unsigned short* __restrict__ tv) {
  int z = blockIdx.z;
  const float* W = (z == 0) ? Wq : (z == 1) ? Wk : Wv;
  unsigned short* Wt = (z == 0) ? tq : (z == 1) ? tk : tv;
  const float scale = (z == 0) ? 0.125f * L2E : 1.0f;  // fold score scale into Wq

  __shared__ float tile[32][33];
  int j0 = blockIdx.x * 32, i0 = blockIdx.y * 32;
  int tx = threadIdx.x & 31, ty = threadIdx.x >> 5;
#pragma unroll
  for (int r = 0; r < 32; r += 8)
    tile[ty + r][tx] = W[(i0 + ty + r) * EMB + j0 + tx];
  __syncthreads();
#pragma unroll
  for (int r = 0; r < 32; r += 8)
    Wt[(j0 + ty + r) * EMB + i0 + tx] = f2bf(tile[tx][ty + r] * scale);
}

// ---------- projection GEMM: 8 waves, 128x128 tile, A fp32 reg-staged 2-deep, B 3-slot ring ----------
// Per-wave output 64x32 (wave grid 2x4). Per iter per wave: 2 gl_lds(B) + 4 loads(A)
// + 2 ds_write -> vbar = s_waitcnt vmcnt(6) + s_barrier (current iter's 6 stay in flight).
__global__ __launch_bounds__(512) void k_proj(
    const float* __restrict__ xq, const float* __restrict__ xk,
    const float* __restrict__ xv,
    const unsigned short* __restrict__ w0, const unsigned short* __restrict__ w1,
    const unsigned short* __restrict__ w2,
    unsigned short* __restrict__ o0, unsigned short* __restrict__ o1,
    unsigned short* __restrict__ o2) {
  int z = blockIdx.z;
  const float* X = (z == 0) ? xq : (z == 1) ? xk : xv;
  const unsigned short* Wt = (z == 0) ? w0 : (z == 1) ? w1 : w2;
  unsigned short* O = (z == 0) ? o0 : (z == 1) ? o1 : o2;

  __shared__ __align__(16) unsigned short As[2][128 * 64];  // 32KB, swizzled
  __shared__ __align__(16) unsigned short Bs[3 * 128 * 64]; // 48KB, 3-slot ring, swizzled

  int tid = threadIdx.x;
  int lane = tid & 63, w = tid >> 6;          // w in 0..7
  int ln15 = lane & 15, lg = lane >> 4;
  int wr = w >> 2, wc = w & 3;                // wave grid 2 x 4
  int row0 = blockIdx.x * 128, col0 = blockIdx.y * 128;

  const char* Xb = (const char*)X;
  const char* Wb = (const char*)Wt;

  f32x4 acc[4][2];
#pragma unroll
  for (int i = 0; i < 4; ++i)
#pragma unroll
    for (int j = 0; j < 2; ++j) acc[i][j] = (f32x4){0.f, 0.f, 0.f, 0.f};

  // per-wave staging: 2 chunks x 1KB for A (16KB/buf over 8 waves) and B (16KB/slot)
  int oc[2], dswz[2];
  size_t srcA[2];
#pragma unroll
  for (int c = 0; c < 2; ++c) {
    oc[c] = w * 2048 + c * 1024 + lane * 16;
    dswz[c] = oc[c] ^ (((oc[c] >> 7) & 7) << 4);
    srcA[c] = (size_t)(row0 + (oc[c] >> 7)) * (EMB * 4) + (size_t)(oc[c] & 127) * 2;
  }

  f32x4 arA[2][2], arB[2][2];
  auto ldA_A = [&](int kt) {
#pragma unroll
    for (int c = 0; c < 2; ++c) {
      const char* p = Xb + srcA[c] + kt * 256;
      arA[c][0] = *(const f32x4*)p;
      arA[c][1] = *(const f32x4*)(p + 16);
    }
  };
  auto ldA_B = [&](int kt) {
#pragma unroll
    for (int c = 0; c < 2; ++c) {
      const char* p = Xb + srcA[c] + kt * 256;
      arB[c][0] = *(const f32x4*)p;
      arB[c][1] = *(const f32x4*)(p + 16);
    }
  };
  auto wrA_A = [&](int buf) {
#pragma unroll
    for (int c = 0; c < 2; ++c) {
      union { unsigned u[4]; bf16x8 v; } pk;
      pk.u[0] = cvt_pk_bf16(arA[c][0][0], arA[c][0][1]);
      pk.u[1] = cvt_pk_bf16(arA[c][0][2], arA[c][0][3]);
      pk.u[2] = cvt_pk_bf16(arA[c][1][0], arA[c][1][1]);
      pk.u[3] = cvt_pk_bf16(arA[c][1][2], arA[c][1][3]);
      *(bf16x8*)((char*)As[buf] + dswz[c]) = pk.v;
    }
  };
  auto wrA_B = [&](int buf) {
#pragma unroll
    for (int c = 0; c < 2; ++c) {
      union { unsigned u[4]; bf16x8 v; } pk;
      pk.u[0] = cvt_pk_bf16(arB[c][0][0], arB[c][0][1]);
      pk.u[1] = cvt_pk_bf16(arB[c][0][2], arB[c][0][3]);
      pk.u[2] = cvt_pk_bf16(arB[c][1][0], arB[c][1][1]);
      pk.u[3] = cvt_pk_bf16(arB[c][1][2], arB[c][1][3]);
      *(bf16x8*)((char*)As[buf] + dswz[c]) = pk.v;
    }
  };
  auto stageB = [&](int slot, int kt) {
#pragma unroll
    for (int c = 0; c < 2; ++c)
      gl_lds16(Wb + (size_t)(col0 + (dswz[c] >> 7)) * (EMB * 2) + kt * 128 + (dswz[c] & 127),
               (char*)Bs + slot * 16384 + w * 2048 + c * 1024);
  };

  auto mfmaStep = [&](int cur, int bslot) {
    const char* bbase = (const char*)Bs + bslot * 16384;
#pragma unroll
    for (int ks = 0; ks < 2; ++ks) {
      bf16x8 a[4], bb[2];
#pragma unroll
      for (int i = 0; i < 4; ++i) {
        int row = wr * 64 + i * 16 + ln15;
        int ba = (row * 128 + ks * 64 + lg * 16) ^ ((row & 7) << 4);
        a[i] = *(const bf16x8*)((const char*)As[cur] + ba);
      }
#pragma unroll
      for (int j = 0; j < 2; ++j) {
        int row = wc * 32 + j * 16 + ln15;
        int ba = (row * 128 + ks * 64 + lg * 16) ^ ((row & 7) << 4);
        bb[j] = *(const bf16x8*)(bbase + ba);
      }
      __builtin_amdgcn_s_setprio(1);
#pragma unroll
      for (int i = 0; i < 4; ++i)
#pragma unroll
        for (int j = 0; j < 2; ++j)
          acc[i][j] = __builtin_amdgcn_mfma_f32_16x16x32_bf16(a[i], bb[j], acc[i][j], 0, 0, 0);
      __builtin_amdgcn_s_setprio(0);
    }
  };

  auto vbar = [&]() {
    asm volatile("s_waitcnt vmcnt(6) lgkmcnt(0)" ::: "memory");
    __builtin_amdgcn_s_barrier();
    __builtin_amdgcn_sched_barrier(0);
  };

  // prologue: A(0)->arA->As[0]; B(0),B(1) staged; A(1)->arB in flight
  ldA_A(0);
  stageB(0, 0);
  stageB(1, 1);
  wrA_A(0);
  ldA_B(1);
  vbar();          // forces B(0) done; B(1)x2 + A(1)x4 = 6 newest stay in flight

#pragma unroll
  for (int kp = 0; kp < 8; ++kp) {
    const int kte = 2 * kp;
    if (kte + 2 <= 15) stageB((kte + 2) % 3, kte + 2);
    if (kte < 14) ldA_A(kte + 2);
    mfmaStep(0, kte % 3);
    wrA_B(1);
    vbar();

    const int kto = 2 * kp + 1;
    if (kto + 2 <= 15) stageB((kto + 2) % 3, kto + 2);
    if (kto < 14) ldA_B(kto + 2);
    mfmaStep(1, kto % 3);
    if (kto < 15) wrA_A(0);
    vbar();
  }

  if (z == 2) {
#pragma unroll
    for (int i = 0; i < 4; ++i) {
#pragma unroll
      for (int j = 0; j < 2; ++j) {
        int col = col0 + wc * 32 + j * 16 + ln15;
        int h = col >> 6, d = col & 63;
        int rowb = row0 + wr * 64 + i * 16 + lg * 4;
        int b = rowb >> 11, s = rowb & (SEQ - 1);
        u16x4 hv;
#pragma unroll
        for (int r = 0; r < 4; ++r) hv[r] = f2bf(acc[i][j][r]);
        *(u16x4*)&O[(((size_t)(b * NH + h) * HD) + d) * SEQ + s] = hv;
      }
    }
  } else {
#pragma unroll
    for (int i = 0; i < 4; ++i) {
#pragma unroll
      for (int j = 0; j < 2; ++j) {
#pragma unroll
        for (int r = 0; r < 4; ++r) {
          int row = row0 + wr * 64 + i * 16 + lg * 4 + r;
          int col = col0 + wc * 32 + j * 16 + ln15;
          int b = row >> 11, s = row & (SEQ - 1);
          int h = col >> 6, d = col & 63;
          O[(((size_t)(b * NH + h) * SEQ) + s) * HD + d] = f2bf(acc[i][j][r]);
        }
      }
    }
  }
}

// ---------- flash attention: att[2] pipeline + ones-MFMA l-sum + counted vmcnt ----------
// (round-12/16 proven 8-wave version, verbatim)
__global__ __launch_bounds__(512) void k_attn(const unsigned short* __restrict__ Q,
                                              const unsigned short* __restrict__ K,
                                              const unsigned short* __restrict__ Vt,
                                              float* __restrict__ out) {
  __shared__ __align__(16) unsigned short Klds[2 * 32 * 64];  // 2 slots x 4KB, [key][d] swz
  __shared__ __align__(16) unsigned short Vlds[2 * 64 * 64];  // 2 slots x 8KB, [d][64key] swz

  const int id = blockIdx.x;
  const int swz = (id & 7) * 64 + (id >> 3);
  const int bh = swz >> 3, qb = swz & 7;
  const int b = bh >> 4, h = bh & 15;

  const int tid = threadIdx.x;
  const int w = tid >> 6, lane = tid & 63;
  const int q31 = lane & 31;
  const int hi = lane >> 5;
  const int q0 = qb * 256 + w * 32;

  const unsigned short* Qb = Q + (size_t)bh * SEQ * HD;
  const char* Kb = (const char*)(K + (size_t)bh * SEQ * HD);
  const char* Vb = (const char*)(Vt + (size_t)bh * HD * SEQ);

  bf16x8 qf[4];
#pragma unroll
  for (int kk = 0; kk < 4; ++kk)
    qf[kk] = *(const bf16x8*)&Qb[(q0 + q31) * HD + kk * 16 + hi * 8];

  f32x16 ctx[2];
#pragma unroll
  for (int db = 0; db < 2; ++db)
#pragma unroll
    for (int r = 0; r < 16; ++r) ctx[db][r] = 0.f;

  f32x16 zero16;
#pragma unroll
  for (int r = 0; r < 16; ++r) zero16[r] = 0.f;
  union { unsigned u[4]; bf16x8 v; } onesf;
#pragma unroll
  for (int r = 0; r < 4; ++r) onesf.u[r] = 0x3F803F80u;
  f32x16 lsum = zero16;  // row-sums of P, C-layout rows == ctx rows

  const int sw = (q31 & 7) << 4;
  int kaddr[4];
#pragma unroll
  for (int kk = 0; kk < 4; ++kk)
    kaddr[kk] = q31 * 128 + (((kk * 32) | (hi * 16)) ^ sw);
  int vaddr[2][2];
#pragma unroll
  for (int pi = 0; pi < 2; ++pi)
#pragma unroll
    for (int j = 0; j < 2; ++j)
      vaddr[pi][j] = q31 * 128 + (((pi * 64) | (j * 32) | (hi * 16)) ^ sw);

  const int o0 = w * 1024 + lane * 16;
  const int os0 = o0 ^ (((o0 >> 7) & 7) << 4);

  auto stageK = [&](int slot, int kt) {
    if (w < 4)
      gl_lds16(Kb + (size_t)kt * 4096 + os0, (char*)Klds + slot * 4096 + w * 1024);
  };
  auto stageV = [&](int slot, int vt) {
    gl_lds16(Vb + (size_t)(os0 >> 7) * (SEQ * 2) + vt * 128 + (os0 & 127),
             (char*)Vlds + slot * 8192 + w * 1024);
  };

  auto barrierC = [&]() {
    if (w < 4) asm volatile("s_waitcnt vmcnt(1)" ::: "memory");
    __builtin_amdgcn_s_barrier();
    __builtin_amdgcn_sched_barrier(0);
  };

  auto qk = [&](f32x16& sx, const char* kbase) {
    __builtin_amdgcn_s_setprio(1);
    bf16x8 kf0 = *(const bf16x8*)(kbase + kaddr[0]);
    sx = __builtin_amdgcn_mfma_f32_32x32x16_bf16(kf0, qf[0], zero16, 0, 0, 0);
#pragma unroll
    for (int kk = 1; kk < 4; ++kk) {
      bf16x8 kf = *(const bf16x8*)(kbase + kaddr[kk]);
      sx = __builtin_amdgcn_mfma_f32_32x32x16_bf16(kf, qf[kk], sx, 0, 0, 0);
    }
    __builtin_amdgcn_s_setprio(0);
  };

  auto smpv = [&](f32x16& sx, int pinIdx, int vb) {
#pragma unroll
    for (int r = 0; r < 16; ++r) sx[r] = __builtin_amdgcn_exp2f(sx[r]);

    unsigned a0 = cvt_pk_bf16(sx[0], sx[1]);
    unsigned a1 = cvt_pk_bf16(sx[2], sx[3]);
    unsigned a2 = cvt_pk_bf16(sx[4], sx[5]);
    unsigned a3 = cvt_pk_bf16(sx[6], sx[7]);
    unsigned a4 = cvt_pk_bf16(sx[8], sx[9]);
    unsigned a5 = cvt_pk_bf16(sx[10], sx[11]);
    unsigned a6 = cvt_pk_bf16(sx[12], sx[13]);
    unsigned a7 = cvt_pk_bf16(sx[14], sx[15]);
    asm volatile("v_permlane32_swap_b32 %0, %1" : "+v"(a0), "+v"(a2));
    asm volatile("v_permlane32_swap_b32 %0, %1" : "+v"(a1), "+v"(a3));
    asm volatile("v_permlane32_swap_b32 %0, %1" : "+v"(a4), "+v"(a6));
    asm volatile("v_permlane32_swap_b32 %0, %1" : "+v"(a5), "+v"(a7));
    union { unsigned u[4]; bf16x8 v; } pa_lo, pa_hi;
    pa_lo.u[0] = a0; pa_lo.u[1] = a1; pa_lo.u[2] = a2; pa_lo.u[3] = a3;
    pa_hi.u[0] = a4; pa_hi.u[1] = a5; pa_hi.u[2] = a6; pa_hi.u[3] = a7;

    const char* vbp = (const char*)Vlds + vb;
    __builtin_amdgcn_s_setprio(1);
    lsum = __builtin_amdgcn_mfma_f32_32x32x16_bf16(pa_lo.v, onesf.v, lsum, 0, 0, 0);
    lsum = __builtin_amdgcn_mfma_f32_32x32x16_bf16(pa_hi.v, onesf.v, lsum, 0, 0, 0);
#pragma unroll
    for (int db = 0; db < 2; ++db) {
      bf16x8 v0 = *(const bf16x8*)(vbp + db * 4096 + vaddr[pinIdx][0]);
      bf16x8 v1 = *(const bf16x8*)(vbp + db * 4096 + vaddr[pinIdx][1]);
      ctx[db] = __builtin_amdgcn_mfma_f32_32x32x16_bf16(pa_lo.v, v0, ctx[db], 0, 0, 0);
      ctx[db] = __builtin_amdgcn_mfma_f32_32x32x16_bf16(pa_hi.v, v1, ctx[db], 0, 0, 0);
    }
    __builtin_amdgcn_s_setprio(0);
  };

  const char* K0 = (const char*)Klds;
  const char* K1 = (const char*)Klds + 4096;
  f32x16 sA, sB;

  stageK(0, 0);
  stageV(0, 0);
  barrierC();
  qk(sA, K0);          // t=0
  stageK(1, 1);
  __syncthreads();     // drains V0 + K(1,1)

  for (int tp = 0; tp < 31; ++tp) {
    const int vb = (tp & 1) << 13;
    qk(sB, K1);
    stageK(0, 2 * tp + 2);
    stageV((tp + 1) & 1, tp + 1);
    smpv(sA, 0, vb);
    barrierC();          // K(2tp+2) ready; V(tp+1) allowed in flight
    qk(sA, K0);
    stageK(1, 2 * tp + 3);
    smpv(sB, 1, vb);
    __syncthreads();     // drains V(tp+1) + K(2tp+3)
  }
  qk(sB, K1);
  smpv(sA, 0, 8192);
  smpv(sB, 1, 8192);

#pragma unroll
  for (int db = 0; db < 2; ++db) {
#pragma unroll
    for (int r = 0; r < 16; ++r) {
      int q = q0 + (r & 3) + 8 * (r >> 2) + 4 * hi;
      out[((size_t)b * SEQ + q) * (NH * HD) + h * HD + db * 32 + q31] =
          ctx[db][r] / lsum[r];
    }
  }
}

extern "C" void kernel_launch(void* const* d_in, const int* in_sizes, int n_in,
                              void* d_out, int out_size, void* d_ws, size_t ws_size,
                              hipStream_t stream) {
  (void)in_sizes; (void)n_in; (void)out_size; (void)ws_size;
  const float* queries = (const float*)d_in[0];
  const float* keys    = (const float*)d_in[1];
  const float* values  = (const float*)d_in[2];
  const float* Wq = (const float*)d_in[3];
  const float* Wk = (const float*)d_in[4];
  const float* Wv = (const float*)d_in[5];
  float* out = (float*)d_out;

  char* ws = (char*)d_ws;
  const size_t MB = 1024 * 1024;
  unsigned short* q_ws = (unsigned short*)(ws);             // [bh][s][d] bf16 (16MB)
  unsigned short* k_ws = (unsigned short*)(ws + 16 * MB);   // [bh][s][d] bf16
  unsigned short* v_ws = (unsigned short*)(ws + 32 * MB);   // [bh][d][s] bf16 (transposed)
  unsigned short* wtq  = (unsigned short*)(ws + 48 * MB);   // Wt[n][k] bf16 (2MB each)
  unsigned short* wtk  = (unsigned short*)(ws + 50 * MB);
  unsigned short* wtv  = (unsigned short*)(ws + 52 * MB);

  k_wt3<<<dim3(32, 32, 3), 256, 0, stream>>>(Wq, Wk, Wv, wtq, wtk, wtv);
  k_proj<<<dim3(64, 8, 3), 512, 0, stream>>>(queries, keys, values,
                                             wtq, wtk, wtv, q_ws, k_ws, v_ws);
  k_attn<<<dim3(512), 512, 0, stream>>>(q_ws, k_ws, v_ws, out);
}

// Round 21
// 159.409 us; speedup vs baseline: 1.1617x; 1.0104x over previous
//
#include <hip/hip_runtime.h>
#include <math.h>

#define SEQ 2048
#define EMB 1024
#define NH 16
#define HD 64
#define BH 64          // B*H = 4*16
#define L2E 1.44269504088896340736f

typedef __attribute__((ext_vector_type(8))) short bf16x8;
typedef __attribute__((ext_vector_type(4))) float f32x4;
typedef __attribute__((ext_vector_type(16))) float f32x16;
typedef __attribute__((ext_vector_type(4))) unsigned short u16x4;

__device__ __forceinline__ unsigned short f2bf(float f) {
  union { float fv; unsigned u; } v; v.fv = f;
  return (unsigned short)((v.u + 0x7FFFu + ((v.u >> 16) & 1u)) >> 16);
}

__device__ __forceinline__ unsigned cvt_pk_bf16(float lo, float hi) {
  unsigned r;
  asm("v_cvt_pk_bf16_f32 %0, %1, %2" : "=v"(r) : "v"(lo), "v"(hi));
  return r;
}

__device__ __forceinline__ void gl_lds16(const void* g, void* l) {
  __builtin_amdgcn_global_load_lds(
      (const __attribute__((address_space(1))) unsigned*)g,
      (__attribute__((address_space(3))) unsigned*)l, 16, 0, 0);
}

// ---------- weight transpose+convert+scale, all 3 weights in one launch ----------
__global__ __launch_bounds__(256) void k_wt3(const float* __restrict__ Wq,
                                             const float* __restrict__ Wk,
                                             const float* __restrict__ Wv,
                                             unsigned short* __restrict__ tq,
                                             unsigned short* __restrict__ tk,
                                             unsigned short* __restrict__ tv) {
  int z = blockIdx.z;
  const float* W = (z == 0) ? Wq : (z == 1) ? Wk : Wv;
  unsigned short* Wt = (z == 0) ? tq : (z == 1) ? tk : tv;
  const float scale = (z == 0) ? 0.125f * L2E : 1.0f;  // fold score scale into Wq

  __shared__ float tile[32][33];
  int j0 = blockIdx.x * 32, i0 = blockIdx.y * 32;
  int tx = threadIdx.x & 31, ty = threadIdx.x >> 5;
#pragma unroll
  for (int r = 0; r < 32; r += 8)
    tile[ty + r][tx] = W[(i0 + ty + r) * EMB + j0 + tx];
  __syncthreads();
#pragma unroll
  for (int r = 0; r < 32; r += 8)
    Wt[(j0 + ty + r) * EMB + i0 + tx] = f2bf(tile[tx][ty + r] * scale);
}

// ---------- projection GEMM: A = fp32 reg-staged 2-deep; B = gl_lds 3-slot ring ----------
// (round-16 measured-best config, verbatim)
__global__ __launch_bounds__(256) void k_proj(
    const float* __restrict__ xq, const float* __restrict__ xk,
    const float* __restrict__ xv,
    const unsigned short* __restrict__ w0, const unsigned short* __restrict__ w1,
    const unsigned short* __restrict__ w2,
    unsigned short* __restrict__ o0, unsigned short* __restrict__ o1,
    unsigned short* __restrict__ o2) {
  int z = blockIdx.z;
  const float* X = (z == 0) ? xq : (z == 1) ? xk : xv;
  const unsigned short* Wt = (z == 0) ? w0 : (z == 1) ? w1 : w2;
  unsigned short* O = (z == 0) ? o0 : (z == 1) ? o1 : o2;

  __shared__ __align__(16) unsigned short As[2][128 * 64];  // 32KB, swizzled
  __shared__ __align__(16) unsigned short Bs[3 * 128 * 64]; // 48KB, 3-slot ring, swizzled

  int tid = threadIdx.x;
  int lane = tid & 63, w = tid >> 6;
  int ln15 = lane & 15, lg = lane >> 4;
  int wr = w >> 1, wc = w & 1;
  int row0 = blockIdx.x * 128, col0 = blockIdx.y * 128;

  const char* Xb = (const char*)X;
  const char* Wb = (const char*)Wt;

  f32x4 acc[4][4];
#pragma unroll
  for (int i = 0; i < 4; ++i)
#pragma unroll
    for (int j = 0; j < 4; ++j) acc[i][j] = (f32x4){0.f, 0.f, 0.f, 0.f};

  int oc[4], dswz[4];
  size_t srcA[4];
#pragma unroll
  for (int c = 0; c < 4; ++c) {
    oc[c] = w * 4096 + c * 1024 + lane * 16;
    dswz[c] = oc[c] ^ (((oc[c] >> 7) & 7) << 4);
    srcA[c] = (size_t)(row0 + (oc[c] >> 7)) * (EMB * 4) + (size_t)(oc[c] & 127) * 2;
  }
  int soB[4];
#pragma unroll
  for (int c = 0; c < 4; ++c) soB[c] = oc[c] ^ (((oc[c] >> 7) & 7) << 4);

  f32x4 arA[4][2], arB[4][2];
  auto ldA_A = [&](int kt) {
#pragma unroll
    for (int c = 0; c < 4; ++c) {
      const char* p = Xb + srcA[c] + kt * 256;
      arA[c][0] = *(const f32x4*)p;
      arA[c][1] = *(const f32x4*)(p + 16);
    }
  };
  auto ldA_B = [&](int kt) {
#pragma unroll
    for (int c = 0; c < 4; ++c) {
      const char* p = Xb + srcA[c] + kt * 256;
      arB[c][0] = *(const f32x4*)p;
      arB[c][1] = *(const f32x4*)(p + 16);
    }
  };
  auto wrA_A = [&](int buf) {
#pragma unroll
    for (int c = 0; c < 4; ++c) {
      union { unsigned u[4]; bf16x8 v; } pk;
      pk.u[0] = cvt_pk_bf16(arA[c][0][0], arA[c][0][1]);
      pk.u[1] = cvt_pk_bf16(arA[c][0][2], arA[c][0][3]);
      pk.u[2] = cvt_pk_bf16(arA[c][1][0], arA[c][1][1]);
      pk.u[3] = cvt_pk_bf16(arA[c][1][2], arA[c][1][3]);
      *(bf16x8*)((char*)As[buf] + dswz[c]) = pk.v;
    }
  };
  auto wrA_B = [&](int buf) {
#pragma unroll
    for (int c = 0; c < 4; ++c) {
      union { unsigned u[4]; bf16x8 v; } pk;
      pk.u[0] = cvt_pk_bf16(arB[c][0][0], arB[c][0][1]);
      pk.u[1] = cvt_pk_bf16(arB[c][0][2], arB[c][0][3]);
      pk.u[2] = cvt_pk_bf16(arB[c][1][0], arB[c][1][1]);
      pk.u[3] = cvt_pk_bf16(arB[c][1][2], arB[c][1][3]);
      *(bf16x8*)((char*)As[buf] + dswz[c]) = pk.v;
    }
  };
  auto stageB = [&](int slot, int kt) {
#pragma unroll
    for (int c = 0; c < 4; ++c)
      gl_lds16(Wb + (size_t)(col0 + (soB[c] >> 7)) * (EMB * 2) + kt * 128 + (soB[c] & 127),
               (char*)Bs + slot * 16384 + w * 4096 + c * 1024);
  };

  auto mfmaStep = [&](int cur, int bslot) {
    const char* bbase = (const char*)Bs + bslot * 16384;
#pragma unroll
    for (int ks = 0; ks < 2; ++ks) {
      bf16x8 a[4], bb[4];
#pragma unroll
      for (int i = 0; i < 4; ++i) {
        int row = wr * 64 + i * 16 + ln15;
        int ba = (row * 128 + ks * 64 + lg * 16) ^ ((row & 7) << 4);
        a[i] = *(const bf16x8*)((const char*)As[cur] + ba);
      }
#pragma unroll
      for (int j = 0; j < 4; ++j) {
        int row = wc * 64 + j * 16 + ln15;
        int ba = (row * 128 + ks * 64 + lg * 16) ^ ((row & 7) << 4);
        bb[j] = *(const bf16x8*)(bbase + ba);
      }
      __builtin_amdgcn_s_setprio(1);
#pragma unroll
      for (int i = 0; i < 4; ++i)
#pragma unroll
        for (int j = 0; j < 4; ++j)
          acc[i][j] = __builtin_amdgcn_mfma_f32_16x16x32_bf16(a[i], bb[j], acc[i][j], 0, 0, 0);
      __builtin_amdgcn_s_setprio(0);
    }
  };

  auto vbar = [&]() {
    asm volatile("s_waitcnt vmcnt(12) lgkmcnt(0)" ::: "memory");
    __builtin_amdgcn_s_barrier();
    __builtin_amdgcn_sched_barrier(0);
  };

  // prologue
  ldA_A(0);
  stageB(0, 0);
  stageB(1, 1);
  wrA_A(0);
  ldA_B(1);
  vbar();

#pragma unroll
  for (int kp = 0; kp < 8; ++kp) {
    const int kte = 2 * kp;
    if (kte + 2 <= 15) stageB((kte + 2) % 3, kte + 2);
    if (kte < 14) ldA_A(kte + 2);
    mfmaStep(0, kte % 3);
    wrA_B(1);
    vbar();

    const int kto = 2 * kp + 1;
    if (kto + 2 <= 15) stageB((kto + 2) % 3, kto + 2);
    if (kto < 14) ldA_B(kto + 2);
    mfmaStep(1, kto % 3);
    if (kto < 15) wrA_A(0);
    vbar();
  }

  if (z == 2) {
#pragma unroll
    for (int i = 0; i < 4; ++i) {
#pragma unroll
      for (int j = 0; j < 4; ++j) {
        int col = col0 + wc * 64 + j * 16 + ln15;
        int h = col >> 6, d = col & 63;
        int rowb = row0 + wr * 64 + i * 16 + lg * 4;
        int b = rowb >> 11, s = rowb & (SEQ - 1);
        u16x4 hv;
#pragma unroll
        for (int r = 0; r < 4; ++r) hv[r] = f2bf(acc[i][j][r]);
        *(u16x4*)&O[(((size_t)(b * NH + h) * HD) + d) * SEQ + s] = hv;
      }
    }
  } else {
#pragma unroll
    for (int i = 0; i < 4; ++i) {
#pragma unroll
      for (int j = 0; j < 4; ++j) {
#pragma unroll
        for (int r = 0; r < 4; ++r) {
          int row = row0 + wr * 64 + i * 16 + lg * 4 + r;
          int col = col0 + wc * 64 + j * 16 + ln15;
          int b = row >> 11, s = row & (SEQ - 1);
          int h = col >> 6, d = col & 63;
          O[(((size_t)(b * NH + h) * SEQ) + s) * HD + d] = f2bf(acc[i][j][r]);
        }
      }
    }
  }
}

// ---------- flash attention: att[2] pipeline + ones-MFMA l-sum + counted vmcnt ----------
// (round-12/16 proven 8-wave version, verbatim)
__global__ __launch_bounds__(512) void k_attn(const unsigned short* __restrict__ Q,
                                              const unsigned short* __restrict__ K,
                                              const unsigned short* __restrict__ Vt,
                                              float* __restrict__ out) {
  __shared__ __align__(16) unsigned short Klds[2 * 32 * 64];  // 2 slots x 4KB, [key][d] swz
  __shared__ __align__(16) unsigned short Vlds[2 * 64 * 64];  // 2 slots x 8KB, [d][64key] swz

  const int id = blockIdx.x;
  const int swz = (id & 7) * 64 + (id >> 3);
  const int bh = swz >> 3, qb = swz & 7;
  const int b = bh >> 4, h = bh & 15;

  const int tid = threadIdx.x;
  const int w = tid >> 6, lane = tid & 63;
  const int q31 = lane & 31;
  const int hi = lane >> 5;
  const int q0 = qb * 256 + w * 32;

  const unsigned short* Qb = Q + (size_t)bh * SEQ * HD;
  const char* Kb = (const char*)(K + (size_t)bh * SEQ * HD);
  const char* Vb = (const char*)(Vt + (size_t)bh * HD * SEQ);

  bf16x8 qf[4];
#pragma unroll
  for (int kk = 0; kk < 4; ++kk)
    qf[kk] = *(const bf16x8*)&Qb[(q0 + q31) * HD + kk * 16 + hi * 8];

  f32x16 ctx[2];
#pragma unroll
  for (int db = 0; db < 2; ++db)
#pragma unroll
    for (int r = 0; r < 16; ++r) ctx[db][r] = 0.f;

  f32x16 zero16;
#pragma unroll
  for (int r = 0; r < 16; ++r) zero16[r] = 0.f;
  union { unsigned u[4]; bf16x8 v; } onesf;
#pragma unroll
  for (int r = 0; r < 4; ++r) onesf.u[r] = 0x3F803F80u;
  f32x16 lsum = zero16;  // row-sums of P, C-layout rows == ctx rows

  const int sw = (q31 & 7) << 4;
  int kaddr[4];
#pragma unroll
  for (int kk = 0; kk < 4; ++kk)
    kaddr[kk] = q31 * 128 + (((kk * 32) | (hi * 16)) ^ sw);
  int vaddr[2][2];
#pragma unroll
  for (int pi = 0; pi < 2; ++pi)
#pragma unroll
    for (int j = 0; j < 2; ++j)
      vaddr[pi][j] = q31 * 128 + (((pi * 64) | (j * 32) | (hi * 16)) ^ sw);

  const int o0 = w * 1024 + lane * 16;
  const int os0 = o0 ^ (((o0 >> 7) & 7) << 4);

  auto stageK = [&](int slot, int kt) {
    if (w < 4)
      gl_lds16(Kb + (size_t)kt * 4096 + os0, (char*)Klds + slot * 4096 + w * 1024);
  };
  auto stageV = [&](int slot, int vt) {
    gl_lds16(Vb + (size_t)(os0 >> 7) * (SEQ * 2) + vt * 128 + (os0 & 127),
             (char*)Vlds + slot * 8192 + w * 1024);
  };

  auto barrierC = [&]() {
    if (w < 4) asm volatile("s_waitcnt vmcnt(1)" ::: "memory");
    __builtin_amdgcn_s_barrier();
    __builtin_amdgcn_sched_barrier(0);
  };

  auto qk = [&](f32x16& sx, const char* kbase) {
    __builtin_amdgcn_s_setprio(1);
    bf16x8 kf0 = *(const bf16x8*)(kbase + kaddr[0]);
    sx = __builtin_amdgcn_mfma_f32_32x32x16_bf16(kf0, qf[0], zero16, 0, 0, 0);
#pragma unroll
    for (int kk = 1; kk < 4; ++kk) {
      bf16x8 kf = *(const bf16x8*)(kbase + kaddr[kk]);
      sx = __builtin_amdgcn_mfma_f32_32x32x16_bf16(kf, qf[kk], sx, 0, 0, 0);
    }
    __builtin_amdgcn_s_setprio(0);
  };

  auto smpv = [&](f32x16& sx, int pinIdx, int vb) {
#pragma unroll
    for (int r = 0; r < 16; ++r) sx[r] = __builtin_amdgcn_exp2f(sx[r]);

    unsigned a0 = cvt_pk_bf16(sx[0], sx[1]);
    unsigned a1 = cvt_pk_bf16(sx[2], sx[3]);
    unsigned a2 = cvt_pk_bf16(sx[4], sx[5]);
    unsigned a3 = cvt_pk_bf16(sx[6], sx[7]);
    unsigned a4 = cvt_pk_bf16(sx[8], sx[9]);
    unsigned a5 = cvt_pk_bf16(sx[10], sx[11]);
    unsigned a6 = cvt_pk_bf16(sx[12], sx[13]);
    unsigned a7 = cvt_pk_bf16(sx[14], sx[15]);
    asm volatile("v_permlane32_swap_b32 %0, %1" : "+v"(a0), "+v"(a2));
    asm volatile("v_permlane32_swap_b32 %0, %1" : "+v"(a1), "+v"(a3));
    asm volatile("v_permlane32_swap_b32 %0, %1" : "+v"(a4), "+v"(a6));
    asm volatile("v_permlane32_swap_b32 %0, %1" : "+v"(a5), "+v"(a7));
    union { unsigned u[4]; bf16x8 v; } pa_lo, pa_hi;
    pa_lo.u[0] = a0; pa_lo.u[1] = a1; pa_lo.u[2] = a2; pa_lo.u[3] = a3;
    pa_hi.u[0] = a4; pa_hi.u[1] = a5; pa_hi.u[2] = a6; pa_hi.u[3] = a7;

    const char* vbp = (const char*)Vlds + vb;
    __builtin_amdgcn_s_setprio(1);
    lsum = __builtin_amdgcn_mfma_f32_32x32x16_bf16(pa_lo.v, onesf.v, lsum, 0, 0, 0);
    lsum = __builtin_amdgcn_mfma_f32_32x32x16_bf16(pa_hi.v, onesf.v, lsum, 0, 0, 0);
#pragma unroll
    for (int db = 0; db < 2; ++db) {
      bf16x8 v0 = *(const bf16x8*)(vbp + db * 4096 + vaddr[pinIdx][0]);
      bf16x8 v1 = *(const bf16x8*)(vbp + db * 4096 + vaddr[pinIdx][1]);
      ctx[db] = __builtin_amdgcn_mfma_f32_32x32x16_bf16(pa_lo.v, v0, ctx[db], 0, 0, 0);
      ctx[db] = __builtin_amdgcn_mfma_f32_32x32x16_bf16(pa_hi.v, v1, ctx[db], 0, 0, 0);
    }
    __builtin_amdgcn_s_setprio(0);
  };

  const char* K0 = (const char*)Klds;
  const char* K1 = (const char*)Klds + 4096;
  f32x16 sA, sB;

  stageK(0, 0);
  stageV(0, 0);
  barrierC();
  qk(sA, K0);          // t=0
  stageK(1, 1);
  __syncthreads();     // drains V0 + K(1,1)

  for (int tp = 0; tp < 31; ++tp) {
    const int vb = (tp & 1) << 13;
    qk(sB, K1);
    stageK(0, 2 * tp + 2);
    stageV((tp + 1) & 1, tp + 1);
    smpv(sA, 0, vb);
    barrierC();          // K(2tp+2) ready; V(tp+1) allowed in flight
    qk(sA, K0);
    stageK(1, 2 * tp + 3);
    smpv(sB, 1, vb);
    __syncthreads();     // drains V(tp+1) + K(2tp+3)
  }
  qk(sB, K1);
  smpv(sA, 0, 8192);
  smpv(sB, 1, 8192);

#pragma unroll
  for (int db = 0; db < 2; ++db) {
#pragma unroll
    for (int r = 0; r < 16; ++r) {
      int q = q0 + (r & 3) + 8 * (r >> 2) + 4 * hi;
      out[((size_t)b * SEQ + q) * (NH * HD) + h * HD + db * 32 + q31] =
          ctx[db][r] / lsum[r];
    }
  }
}

extern "C" void kernel_launch(void* const* d_in, const int* in_sizes, int n_in,
                              void* d_out, int out_size, void* d_ws, size_t ws_size,
                              hipStream_t stream) {
  (void)in_sizes; (void)n_in; (void)out_size; (void)ws_size;
  const float* queries = (const float*)d_in[0];
  const float* keys    = (const float*)d_in[1];
  const float* values  = (const float*)d_in[2];
  const float* Wq = (const float*)d_in[3];
  const float* Wk = (const float*)d_in[4];
  const float* Wv = (const float*)d_in[5];
  float* out = (float*)d_out;

  char* ws = (char*)d_ws;
  const size_t MB = 1024 * 1024;
  unsigned short* q_ws = (unsigned short*)(ws);             // [bh][s][d] bf16 (16MB)
  unsigned short* k_ws = (unsigned short*)(ws + 16 * MB);   // [bh][s][d] bf16
  unsigned short* v_ws = (unsigned short*)(ws + 32 * MB);   // [bh][d][s] bf16 (transposed)
  unsigned short* wtq  = (unsigned short*)(ws + 48 * MB);   // Wt[n][k] bf16 (2MB each)
  unsigned short* wtk  = (unsigned short*)(ws + 50 * MB);
  unsigned short* wtv  = (unsigned short*)(ws + 52 * MB);

  k_wt3<<<dim3(32, 32, 3), 256, 0, stream>>>(Wq, Wk, Wv, wtq, wtk, wtv);
  k_proj<<<dim3(64, 8, 3), 256, 0, stream>>>(queries, keys, values,
                                             wtq, wtk, wtv, q_ws, k_ws, v_ws);
  k_attn<<<dim3(512), 512, 0, stream>>>(q_ws, k_ws, v_ws, out);
}